// Round 9
// baseline (162.329 us; speedup 1.0000x reference)
//
#include <hip/hip_runtime.h>
#include <hip/hip_bf16.h>

// Causal SDPA, B=2 H=16 S=2048 D=64, fp32 in/out.
// R9: like R8's KV-half split, but ALL 1024 jobs co-resident (no LDS pad,
// 4 blocks/CU = 16 waves/CU) with a statically balanced (jb,half)->bid map:
// under XCD round-robin, bids b,b+256,b+512,b+768 share a CU; the map makes
// each CU's four job periods sum to exactly 34. Tree-max softmax reduce.

#define S_ 2048
#define D_ 64
#define NBH 32

typedef __bf16 bf16x8 __attribute__((ext_vector_type(8)));
typedef float f32x16 __attribute__((ext_vector_type(16)));
typedef unsigned short u16x4 __attribute__((ext_vector_type(4)));
typedef unsigned short u16x8 __attribute__((ext_vector_type(8)));
typedef unsigned int u32;
typedef u32 u32x4 __attribute__((ext_vector_type(4)));

static __device__ __forceinline__ unsigned short bfb(float f) {
    return __builtin_bit_cast(unsigned short, (__bf16)f);   // HW RNE cvt
}
static __device__ __forceinline__ u32 pk2(float lo, float hi) {
    return (u32)bfb(lo) | ((u32)bfb(hi) << 16);
}

// ---- prep: K f32->bf16 flat; V f32 [s][d] -> bf16 transposed [d][s]
__global__ __launch_bounds__(256)
void prep_kv(const float* __restrict__ K, const float* __restrict__ V,
             unsigned short* __restrict__ Kbf, unsigned short* __restrict__ Vt) {
    const int bh = blockIdx.x >> 5;
    const int kvbase = (blockIdx.x & 31) << 6;

    const float* Ks = K + (size_t)bh * S_ * D_ + (size_t)kvbase * D_;
    unsigned short* Kd = Kbf + (size_t)bh * S_ * D_ + (size_t)kvbase * D_;
    #pragma unroll
    for (int i = 0; i < 4; ++i) {
        const int p = i * 256 + threadIdx.x;
        float4 x = reinterpret_cast<const float4*>(Ks)[p];
        u16x4 o = { bfb(x.x), bfb(x.y), bfb(x.z), bfb(x.w) };
        reinterpret_cast<u16x4*>(Kd)[p] = o;
    }

    __shared__ float Vl[64][65];
    const float* Vb = V + (size_t)bh * S_ * D_ + (size_t)kvbase * D_;
    #pragma unroll
    for (int i = 0; i < 4; ++i) {
        const int flat = i * 1024 + threadIdx.x * 4;
        const int kv = flat >> 6, d = flat & 63;
        float4 x = *reinterpret_cast<const float4*>(Vb + kv * D_ + d);
        Vl[kv][d] = x.x; Vl[kv][d + 1] = x.y; Vl[kv][d + 2] = x.z; Vl[kv][d + 3] = x.w;
    }
    __syncthreads();
    unsigned short* Vo = Vt + (size_t)bh * D_ * S_;
    #pragma unroll
    for (int i = 0; i < 2; ++i) {
        const int p = i * 256 + threadIdx.x;
        const int d = p >> 3, c = p & 7;
        u16x8 o;
        #pragma unroll
        for (int j = 0; j < 8; ++j) o[j] = bfb(Vl[c * 8 + j][d]);
        *reinterpret_cast<u16x8*>(Vo + d * S_ + kvbase + c * 8) = o;
    }
}

#define MFMA32(a, b, c) __builtin_amdgcn_mfma_f32_32x32x16_bf16((a), (b), (c), 0, 0, 0)

// Shared tile-compute body used by both attention kernels.
#define TILE_BODY(Kb_, Vb_, doMask, qg_expr)                                     \
    {                                                                            \
        f32x16 s0, s1;                                                           \
        _Pragma("unroll")                                                        \
        for (int r = 0; r < 16; ++r) { s0[r] = 0.f; s1[r] = 0.f; }               \
        __builtin_amdgcn_s_setprio(1);                                           \
        _Pragma("unroll")                                                        \
        for (int ks = 0; ks < 4; ++ks) {                                         \
            const int cc = 2 * ks + hi;                                          \
            bf16x8 k0 = *reinterpret_cast<const bf16x8*>(                        \
                &Kb_[((lq)*8      + (cc ^ (lq & 7))) * 8]);                      \
            bf16x8 k1 = *reinterpret_cast<const bf16x8*>(                        \
                &Kb_[((32 + lq)*8 + (cc ^ (lq & 7))) * 8]);                      \
            s0 = MFMA32(k0, qf[ks], s0);                                         \
            s1 = MFMA32(k1, qf[ks], s1);                                         \
        }                                                                        \
        __builtin_amdgcn_s_setprio(0);                                           \
        if (doMask) {                                                            \
            const int qg = (qg_expr);                                            \
            _Pragma("unroll")                                                    \
            for (int r = 0; r < 16; ++r) {                                       \
                const int kv0 = (r & 3) + 8 * (r >> 2) + 4 * hi;                 \
                if (kv0 > qg)      s0[r] = -__builtin_inff();                    \
                if (kv0 + 32 > qg) s1[r] = -__builtin_inff();                    \
            }                                                                    \
        }                                                                        \
        float mx[16];                                                            \
        _Pragma("unroll")                                                        \
        for (int r = 0; r < 16; ++r) mx[r] = fmaxf(s0[r], s1[r]);                \
        _Pragma("unroll")                                                        \
        for (int off = 8; off >= 1; off >>= 1)                                   \
            for (int r = 0; r < off; ++r) mx[r] = fmaxf(mx[r], mx[r + off]);     \
        const float v = fmaxf(mx[0], __shfl_xor(mx[0], 32));                     \
        if (__any(v > m_ + 8.0f ? 1 : 0)) {                                      \
            const float mn = fmaxf(m_, v);                                       \
            const float al = __builtin_amdgcn_exp2f(m_ - mn);                    \
            m_ = mn;                                                             \
            ssum[0] *= al;                                                       \
            _Pragma("unroll")                                                    \
            for (int r = 0; r < 16; ++r) { oa0[r] *= al; oa1[r] *= al; }         \
        }                                                                        \
        _Pragma("unroll")                                                        \
        for (int r = 0; r < 16; ++r) {                                           \
            s0[r] = __builtin_amdgcn_exp2f(s0[r] - m_);                          \
            s1[r] = __builtin_amdgcn_exp2f(s1[r] - m_);                          \
        }                                                                        \
        u32 c0[4][2], c1[4][2];                                                  \
        _Pragma("unroll")                                                        \
        for (int tq = 0; tq < 4; ++tq) {                                         \
            c0[tq][0] = pk2(s0[4*tq+0], s0[4*tq+1]);                             \
            c0[tq][1] = pk2(s0[4*tq+2], s0[4*tq+3]);                             \
            c1[tq][0] = pk2(s1[4*tq+0], s1[4*tq+1]);                             \
            c1[tq][1] = pk2(s1[4*tq+2], s1[4*tq+3]);                             \
        }                                                                        \
        __builtin_amdgcn_s_setprio(1);                                           \
        PVSTEP(0, c0, 0) PVSTEP(1, c0, 2) PVSTEP(2, c1, 0) PVSTEP(3, c1, 2)      \
        __builtin_amdgcn_s_setprio(0);                                           \
    }

#define PVSTEP(KS, C, TL) {                                                      \
    u32 a0 = C[TL][0], a1 = C[TL][1], b0 = C[TL+1][0], b1 = C[TL+1][1];          \
    asm volatile("v_permlane32_swap_b32 %0, %1" : "+v"(a0), "+v"(b0));           \
    asm volatile("v_permlane32_swap_b32 %0, %1" : "+v"(a1), "+v"(b1));           \
    u32x4 w = { a0, a1, b0, b1 };                                                \
    bf16x8 pf = __builtin_bit_cast(bf16x8, w);                                   \
    const int cc = 2*(KS) + hi;                                                  \
    bf16x8 v0 = *reinterpret_cast<const bf16x8*>(                                \
        &Vb_[((lq)*8      + (cc ^ (lq & 7))) * 8]);                              \
    bf16x8 v1 = *reinterpret_cast<const bf16x8*>(                                \
        &Vb_[((32 + lq)*8 + (cc ^ (lq & 7))) * 8]);                              \
    oa0 = MFMA32(v0, pf, oa0);                                                   \
    oa1 = MFMA32(v1, pf, oa1);                                                   \
    ssum = MFMA32(ones, pf, ssum); }

// ---- common prologue macro: indices, Q frags, staging setup, accumulators
#define ATTN_PROLOGUE(Q0W_EXPR)                                                  \
    const int tid  = threadIdx.x;                                                \
    const int wq   = tid >> 6;                                                   \
    const int lane = tid & 63;                                                   \
    const int lq   = lane & 31;                                                  \
    const int hi   = lane >> 5;                                                  \
    const int q0w  = (Q0W_EXPR);                                                 \
    const unsigned short* Kg = Kbf  + (size_t)bh * S_ * D_;                      \
    const unsigned short* Vg = Vtbf + (size_t)bh * D_ * S_;                      \
    const float qscale = 0.18033688011112042f;                                   \
    bf16x8 qf[4];                                                                \
    {                                                                            \
        const float* qsrc = Q + ((size_t)bh * S_ + q0w + lq) * D_;               \
        _Pragma("unroll")                                                        \
        for (int ks = 0; ks < 4; ++ks) {                                         \
            const float* p = qsrc + ks * 16 + hi * 8;                            \
            float4 x = *reinterpret_cast<const float4*>(p);                      \
            float4 y = *reinterpret_cast<const float4*>(p + 4);                  \
            union { unsigned short u[8]; bf16x8 v; } tt;                         \
            tt.u[0] = bfb(x.x * qscale); tt.u[1] = bfb(x.y * qscale);            \
            tt.u[2] = bfb(x.z * qscale); tt.u[3] = bfb(x.w * qscale);            \
            tt.u[4] = bfb(y.x * qscale); tt.u[5] = bfb(y.y * qscale);            \
            tt.u[6] = bfb(y.z * qscale); tt.u[7] = bfb(y.w * qscale);            \
            qf[ks] = tt.v;                                                       \
        }                                                                        \
    }                                                                            \
    bf16x8 ones;                                                                 \
    _Pragma("unroll")                                                            \
    for (int i = 0; i < 8; ++i) ones[i] = (__bf16)1.0f;                          \
    const unsigned short* kSrc[2];                                               \
    const unsigned short* vSrc[2];                                               \
    _Pragma("unroll")                                                            \
    for (int i = 0; i < 2; ++i) {                                                \
        const int p = i * 256 + tid, row = p >> 3;                               \
        const int sc = (p & 7) ^ (row & 7);                                      \
        kSrc[i] = Kg + row * 64 + sc * 8;                                        \
        vSrc[i] = Vg + (size_t)row * S_ + sc * 8;                                \
    }                                                                            \
    auto stage = [&](int buf, int t) {                                           \
        _Pragma("unroll")                                                        \
        for (int i = 0; i < 2; ++i) {                                            \
            const int p = i * 256 + tid;                                         \
            __builtin_amdgcn_global_load_lds(                                    \
                (const __attribute__((address_space(1))) void*)(kSrc[i] + t * 4096), \
                (__attribute__((address_space(3))) void*)&Kl[buf][p * 8], 16, 0, 0); \
            __builtin_amdgcn_global_load_lds(                                    \
                (const __attribute__((address_space(1))) void*)(vSrc[i] + t * 64),   \
                (__attribute__((address_space(3))) void*)&Vl[buf][p * 8], 16, 0, 0); \
        }                                                                        \
    };                                                                           \
    f32x16 oa0, oa1, ssum;                                                       \
    _Pragma("unroll")                                                            \
    for (int r = 0; r < 16; ++r) { oa0[r] = 0.f; oa1[r] = 0.f; ssum[r] = 0.f; }  \
    float m_ = -__builtin_inff();

// ---- R9 split kernel: job = (bh, band jb, KV half); balanced static map
__global__ __launch_bounds__(256, 4)
void attn_split(const float* __restrict__ Q, const unsigned short* __restrict__ Kbf,
                const unsigned short* __restrict__ Vtbf,
                float* __restrict__ OA, float* __restrict__ OB,
                float* __restrict__ stats) {
    const int bid  = blockIdx.x;
    // Balanced map: bids {b, b+256, b+512, b+768} share a CU under XCD
    // round-robin; periods (jb+1) of a CU's four jobs sum to 34 for all CUs.
    const int idx  = bid >> 5;               // 0..31
    const int half = idx >> 4;
    const int jb   = half ? (idx - 16) : (15 - idx);
    const int bh   = bid & 31;

    __shared__ __align__(16) unsigned short Kl[2][4096];
    __shared__ __align__(16) unsigned short Vl[2][4096];

    ATTN_PROLOGUE(jb * 128 + wq * 32)

    const int t0   = half ? (jb + 1) : 0;
    const int tEnd = half ? (2 * jb + 2) : (jb + 1);
    const int nkv_w = 2 * jb + 1 + (wq >> 1);     // wave's absolute tile count

    stage(t0 & 1, t0);
    __syncthreads();

    for (int t = t0; t < tEnd; ++t) {
        if (t + 1 < tEnd) stage((t + 1) & 1, t + 1);
        if (t < nkv_w) {
            const unsigned short* Kb_ = Kl[t & 1];
            const unsigned short* Vb_ = Vl[t & 1];
            TILE_BODY(Kb_, Vb_, (t == nkv_w - 1), q0w + lq - t * 64)
        }
        __syncthreads();
    }

    // ---- partial epilogue: unnormalized O_acc + (m, l)
    float* dst = (half ? OB : OA) + ((size_t)bh * S_ + q0w + lq) * D_;
    #pragma unroll
    for (int g = 0; g < 4; ++g) {
        float4 o0 = { oa0[4*g+0], oa0[4*g+1], oa0[4*g+2], oa0[4*g+3] };
        *reinterpret_cast<float4*>(&dst[8*g + 4*hi]) = o0;
        float4 o1 = { oa1[4*g+0], oa1[4*g+1], oa1[4*g+2], oa1[4*g+3] };
        *reinterpret_cast<float4*>(&dst[32 + 8*g + 4*hi]) = o1;
    }
    if (hi == 0) {
        float* st = stats + (((size_t)bh << 11) + q0w + lq) * 4 + (half ? 2 : 0);
        st[0] = m_;
        st[1] = ssum[0];
    }
}

// ---- combine: O = (OA*wA + OB*wB) / (lA*wA + lB*wB)
__global__ __launch_bounds__(256)
void combine(float* __restrict__ OA, const float* __restrict__ OB,
             const float4* __restrict__ stats) {
    const int p = blockIdx.x * 256 + threadIdx.x;        // float4 index
    const float4 s = stats[p >> 4];
    const float m  = fmaxf(s.x, s.z);
    const float wA = __builtin_amdgcn_exp2f(s.x - m);
    const float wB = __builtin_amdgcn_exp2f(s.z - m);
    const float inv = 1.0f / (s.y * wA + s.w * wB);
    float4 a = reinterpret_cast<float4*>(OA)[p];
    float4 b = reinterpret_cast<const float4*>(OB)[p];
    float4 o = { (a.x * wA + b.x * wB) * inv, (a.y * wA + b.y * wB) * inv,
                 (a.z * wA + b.z * wB) * inv, (a.w * wA + b.w * wB) * inv };
    reinterpret_cast<float4*>(OA)[p] = o;
}

// ---- R6 fallback (single-pass, used if ws too small for partials)
__global__ __launch_bounds__(256, 2)
void attn_fwd6(const float* __restrict__ Q, const unsigned short* __restrict__ Kbf,
               const unsigned short* __restrict__ Vtbf, float* __restrict__ O) {
    const int bid = blockIdx.x;
    const int bh  = bid & 31;
    const int jb  = 15 - (bid >> 5);

    __shared__ __align__(16) unsigned short Kl[2][4096];
    __shared__ __align__(16) unsigned short Vl[2][4096];

    ATTN_PROLOGUE(jb * 128 + wq * 32)

    const int nkv_b = 2 * jb + 2;
    const int nkv_w = 2 * jb + 1 + (wq >> 1);

    stage(0, 0);
    __syncthreads();

    for (int t = 0; t < nkv_b; ++t) {
        if (t + 1 < nkv_b) stage((t + 1) & 1, t + 1);
        if (t < nkv_w) {
            const unsigned short* Kb_ = Kl[t & 1];
            const unsigned short* Vb_ = Vl[t & 1];
            TILE_BODY(Kb_, Vb_, (t == nkv_w - 1), q0w + lq - t * 64)
        }
        __syncthreads();
    }

    const float inv = 1.0f / ssum[0];
    float* Ob = O + ((size_t)bh * S_ + q0w + lq) * D_;
    #pragma unroll
    for (int g = 0; g < 4; ++g) {
        float4 o0 = { oa0[4*g+0]*inv, oa0[4*g+1]*inv, oa0[4*g+2]*inv, oa0[4*g+3]*inv };
        *reinterpret_cast<float4*>(&Ob[8*g + 4*hi]) = o0;
        float4 o1 = { oa1[4*g+0]*inv, oa1[4*g+1]*inv, oa1[4*g+2]*inv, oa1[4*g+3]*inv };
        *reinterpret_cast<float4*>(&Ob[32 + 8*g + 4*hi]) = o1;
    }
}

extern "C" void kernel_launch(void* const* d_in, const int* in_sizes, int n_in,
                              void* d_out, int out_size, void* d_ws, size_t ws_size,
                              hipStream_t stream) {
    const float* Q = (const float*)d_in[0];
    const float* K = (const float*)d_in[1];
    const float* V = (const float*)d_in[2];
    // d_in[3] = mask: exact causal tril -> applied analytically.
    float* O = (float*)d_out;

    unsigned short* Kbf = (unsigned short*)d_ws;                       // 8 MB
    unsigned short* Vt  = Kbf + (size_t)NBH * S_ * D_;                 // 8 MB

    hipLaunchKernelGGL(prep_kv, dim3(1024), dim3(256), 0, stream, K, V, Kbf, Vt);

    const size_t needed = (size_t)NBH * S_ * D_ * 2 * 2      // Kbf + Vt
                        + (size_t)NBH * S_ * D_ * 4          // OB partial
                        + (size_t)NBH * S_ * 16;             // stats
    if (ws_size >= needed) {
        float* OB    = (float*)(Vt + (size_t)NBH * S_ * D_);           // 16 MB
        float* stats = OB + (size_t)NBH * S_ * D_;                     // 1 MB
        // 32KB static LDS, 4 blocks/CU -> all 1024 jobs co-resident
        hipLaunchKernelGGL(attn_split, dim3(1024), dim3(256), 0, stream,
                           Q, Kbf, Vt, O, OB, stats);
        hipLaunchKernelGGL(combine, dim3(4096), dim3(256), 0, stream,
                           O, OB, (const float4*)stats);
    } else {
        hipLaunchKernelGGL(attn_fwd6, dim3(512), dim3(256), 0, stream,
                           Q, Kbf, Vt, O);
    }
}

// Round 10
// 139.672 us; speedup vs baseline: 1.1622x; 1.1622x over previous
//
#include <hip/hip_runtime.h>
#include <hip/hip_bf16.h>

// Causal SDPA, B=2 H=16 S=2048 D=64, fp32 in/out.
// R10: barrier-free. prep writes K and V^T in MFMA-fragment-major bf16 layout
// ([bh][t][h][ks][lane]*16B), so each wave loads whole K/V tiles into registers
// via perfectly-coalesced dwordx4 loads. No LDS, no __syncthreads in the attn
// kernel; each wave = independent 32-q-row job; heavy/light jobs paired per CU
// (sum = 33 tiles); per-XCD KV working set = 4 bh = 2MB (L2-resident).

#define S_ 2048
#define D_ 64
#define NBH 32

typedef __bf16 bf16x8 __attribute__((ext_vector_type(8)));
typedef float f32x16 __attribute__((ext_vector_type(16)));
typedef unsigned short u16x8 __attribute__((ext_vector_type(8)));
typedef unsigned int u32;
typedef u32 u32x4 __attribute__((ext_vector_type(4)));

static __device__ __forceinline__ unsigned short bfb(float f) {
    return __builtin_bit_cast(unsigned short, (__bf16)f);   // HW RNE cvt
}
static __device__ __forceinline__ u32 pk2(float lo, float hi) {
    return (u32)bfb(lo) | ((u32)bfb(hi) << 16);
}

// ---- prep: per (bh,t) 64x64 tile -> fragment-major bf16 K and V^T arrays.
// Kf unit u = h*256 + ks*64 + lane (lane=hi*32+lq), 16B each:
//   Kf[u] = K[bh][t*64 + h*32 + lq][8*(2ks+hi) .. +8]
//   Vf[u] = V[bh][t*64 + 8*(2ks+hi) .. +8][h*32 + lq]   (transposed)
__global__ __launch_bounds__(256)
void prep_frag(const float* __restrict__ K, const float* __restrict__ V,
               unsigned short* __restrict__ Kf, unsigned short* __restrict__ Vf) {
    const int bh = blockIdx.x >> 5;
    const int t  = blockIdx.x & 31;
    __shared__ float Ka[64][65];
    __shared__ float Va[64][65];
    const float* Ks = K + ((size_t)bh * S_ + t * 64) * D_;
    const float* Vs = V + ((size_t)bh * S_ + t * 64) * D_;
    #pragma unroll
    for (int i = 0; i < 4; ++i) {
        const int flat = i * 1024 + threadIdx.x * 4;
        const int s = flat >> 6, d = flat & 63;
        float4 kx = *reinterpret_cast<const float4*>(Ks + s * D_ + d);
        Ka[s][d] = kx.x; Ka[s][d+1] = kx.y; Ka[s][d+2] = kx.z; Ka[s][d+3] = kx.w;
        float4 vx = *reinterpret_cast<const float4*>(Vs + s * D_ + d);
        Va[s][d] = vx.x; Va[s][d+1] = vx.y; Va[s][d+2] = vx.z; Va[s][d+3] = vx.w;
    }
    __syncthreads();
    const size_t tb = ((size_t)bh * 32 + t) * 512;   // 16B-unit base
    #pragma unroll
    for (int i = 0; i < 2; ++i) {
        const int u  = i * 256 + threadIdx.x;
        const int h  = u >> 8, ks = (u >> 6) & 3, h2 = (u >> 5) & 1, l2 = u & 31;
        const int d0 = 8 * (2 * ks + h2);
        u16x8 ok, ov;
        #pragma unroll
        for (int j = 0; j < 8; ++j) {
            ok[j] = bfb(Ka[h * 32 + l2][d0 + j]);
            ov[j] = bfb(Va[d0 + j][h * 32 + l2]);
        }
        *reinterpret_cast<u16x8*>(Kf + (tb + u) * 8) = ok;
        *reinterpret_cast<u16x8*>(Vf + (tb + u) * 8) = ov;
    }
}

#define MFMA32(a, b, c) __builtin_amdgcn_mfma_f32_32x32x16_bf16((a), (b), (c), 0, 0, 0)

// Load all 8 fragments of one tile (4096 u16 per tile) — coalesced 1KB/instr.
#define LOADF(DST, BASE, T) { \
    const unsigned short* fb_ = (BASE) + (size_t)(T) * 4096 + lane * 8; \
    DST[0] = *reinterpret_cast<const bf16x8*>(fb_); \
    DST[1] = *reinterpret_cast<const bf16x8*>(fb_ + 512); \
    DST[2] = *reinterpret_cast<const bf16x8*>(fb_ + 1024); \
    DST[3] = *reinterpret_cast<const bf16x8*>(fb_ + 1536); \
    DST[4] = *reinterpret_cast<const bf16x8*>(fb_ + 2048); \
    DST[5] = *reinterpret_cast<const bf16x8*>(fb_ + 2560); \
    DST[6] = *reinterpret_cast<const bf16x8*>(fb_ + 3072); \
    DST[7] = *reinterpret_cast<const bf16x8*>(fb_ + 3584); }

#define PVSTEP(KS, C, TL) { \
    u32 a0 = C[TL][0], a1 = C[TL][1], b0 = C[TL+1][0], b1 = C[TL+1][1]; \
    asm volatile("v_permlane32_swap_b32 %0, %1" : "+v"(a0), "+v"(b0)); \
    asm volatile("v_permlane32_swap_b32 %0, %1" : "+v"(a1), "+v"(b1)); \
    u32x4 w = { a0, a1, b0, b1 }; \
    bf16x8 pf = __builtin_bit_cast(bf16x8, w); \
    oa0 = MFMA32(vA[KS],     pf, oa0); \
    oa1 = MFMA32(vA[4 + KS], pf, oa1); }

__global__ __launch_bounds__(256, 2)
void attn_frag(const float* __restrict__ Q, const unsigned short* __restrict__ Kf,
               const unsigned short* __restrict__ Vf, float* __restrict__ O) {
    const int tid  = threadIdx.x;
    const int wq   = tid >> 6;
    const int lane = tid & 63;
    const int lq   = lane & 31;
    const int hi   = lane >> 5;

    // job map: blocks 0..255 = heavy slices (qs 63..32), 256..511 = light
    // complements; under XCD round-robin a CU's pairs sum to 33 tiles, and
    // XCD x only touches bh in {4x..4x+3} (KV L2-resident).
    const int wid = blockIdx.x * 4 + wq;
    int qs, bh;
    if (wid < 1024) { qs = 63 - (wid >> 5); bh = wid & 31; }
    else            { qs = (wid - 1024) >> 5; bh = (wid - 1024) & 31; }
    const int q0w = qs * 32;
    const int nt  = (qs >> 1) + 1;

    const unsigned short* Kg = Kf + (size_t)bh * 131072;   // 32 tiles * 4096 u16
    const unsigned short* Vg = Vf + (size_t)bh * 131072;

    // ---- Q B-frags (col=lq=q, k(d)=16ks+8hi+i), scaled log2(e)/8
    const float qscale = 0.18033688011112042f;
    bf16x8 qf[4];
    {
        const float* qsrc = Q + ((size_t)bh * S_ + q0w + lq) * D_;
        #pragma unroll
        for (int ks = 0; ks < 4; ++ks) {
            const float* p = qsrc + ks * 16 + hi * 8;
            float4 x = *reinterpret_cast<const float4*>(p);
            float4 y = *reinterpret_cast<const float4*>(p + 4);
            union { unsigned short u[8]; bf16x8 v; } tt;
            tt.u[0] = bfb(x.x * qscale); tt.u[1] = bfb(x.y * qscale);
            tt.u[2] = bfb(x.z * qscale); tt.u[3] = bfb(x.w * qscale);
            tt.u[4] = bfb(y.x * qscale); tt.u[5] = bfb(y.y * qscale);
            tt.u[6] = bfb(y.z * qscale); tt.u[7] = bfb(y.w * qscale);
            qf[ks] = tt.v;
        }
    }

    f32x16 oa0, oa1;
    #pragma unroll
    for (int r = 0; r < 16; ++r) { oa0[r] = 0.f; oa1[r] = 0.f; }
    float m_ = -__builtin_inff(), l_ = 0.f;

    bf16x8 kA[8], vA[8];
    LOADF(kA, Kg, 0)
    LOADF(vA, Vg, 0)

    for (int t = 0; t < nt; ++t) {
        const int tn = (t + 1 < 32) ? (t + 1) : 31;   // clamped prefetch target

        // ---- S^T = K · Q^T
        f32x16 s0, s1;
        #pragma unroll
        for (int r = 0; r < 16; ++r) { s0[r] = 0.f; s1[r] = 0.f; }
        __builtin_amdgcn_s_setprio(1);
        #pragma unroll
        for (int ks = 0; ks < 4; ++ks) {
            s0 = MFMA32(kA[ks],     qf[ks], s0);
            s1 = MFMA32(kA[4 + ks], qf[ks], s1);
        }
        __builtin_amdgcn_s_setprio(0);

        LOADF(kA, Kg, tn)                 // prefetch next K over current (WAR ok)

        // ---- causal mask (diagonal tile = this wave's last)
        if (t == nt - 1) {
            const int qg = q0w + lq - t * 64;
            #pragma unroll
            for (int r = 0; r < 16; ++r) {
                const int kv0 = (r & 3) + 8 * (r >> 2) + 4 * hi;
                if (kv0 > qg)      s0[r] = -__builtin_inff();
                if (kv0 + 32 > qg) s1[r] = -__builtin_inff();
            }
        }

        // ---- online softmax (base-2), tree max, defer-max THR=8
        float mx[16];
        #pragma unroll
        for (int r = 0; r < 16; ++r) mx[r] = fmaxf(s0[r], s1[r]);
        #pragma unroll
        for (int off = 8; off >= 1; off >>= 1)
            for (int r = 0; r < off; ++r) mx[r] = fmaxf(mx[r], mx[r + off]);
        const float v = fmaxf(mx[0], __shfl_xor(mx[0], 32));
        if (__any(v > m_ + 8.0f ? 1 : 0)) {
            const float mn = fmaxf(m_, v);
            const float al = __builtin_amdgcn_exp2f(m_ - mn);
            m_ = mn;
            l_ *= al;
            #pragma unroll
            for (int r = 0; r < 16; ++r) { oa0[r] *= al; oa1[r] *= al; }
        }
        #pragma unroll
        for (int r = 0; r < 16; ++r) {
            s0[r] = __builtin_amdgcn_exp2f(s0[r] - m_);
            s1[r] = __builtin_amdgcn_exp2f(s1[r] - m_);
        }

        // ---- row-sum (VALU tree) into l_
        {
            float ts[16];
            #pragma unroll
            for (int r = 0; r < 16; ++r) ts[r] = s0[r] + s1[r];
            #pragma unroll
            for (int off = 8; off >= 1; off >>= 1)
                for (int r = 0; r < off; ++r) ts[r] += ts[r + off];
            l_ += ts[0] + __shfl_xor(ts[0], 32);
        }

        // ---- pack P^T to bf16 pairs
        u32 c0[4][2], c1[4][2];
        #pragma unroll
        for (int tq = 0; tq < 4; ++tq) {
            c0[tq][0] = pk2(s0[4*tq+0], s0[4*tq+1]);
            c0[tq][1] = pk2(s0[4*tq+2], s0[4*tq+3]);
            c1[tq][0] = pk2(s1[4*tq+0], s1[4*tq+1]);
            c1[tq][1] = pk2(s1[4*tq+2], s1[4*tq+3]);
        }

        // ---- O^T += V^T · P^T
        __builtin_amdgcn_s_setprio(1);
        PVSTEP(0, c0, 0) PVSTEP(1, c0, 2) PVSTEP(2, c1, 0) PVSTEP(3, c1, 2)
        __builtin_amdgcn_s_setprio(0);

        LOADF(vA, Vg, tn)                 // prefetch next V over current
    }

    // ---- epilogue: O[q][d] = O^T / l ; d = (r&3)+8*(r>>2)+4*hi (+32)
    const float inv = 1.0f / l_;
    float* Ob = O + ((size_t)bh * S_ + q0w + lq) * D_;
    #pragma unroll
    for (int g = 0; g < 4; ++g) {
        float4 o0 = { oa0[4*g+0]*inv, oa0[4*g+1]*inv, oa0[4*g+2]*inv, oa0[4*g+3]*inv };
        *reinterpret_cast<float4*>(&Ob[8*g + 4*hi]) = o0;
        float4 o1 = { oa1[4*g+0]*inv, oa1[4*g+1]*inv, oa1[4*g+2]*inv, oa1[4*g+3]*inv };
        *reinterpret_cast<float4*>(&Ob[32 + 8*g + 4*hi]) = o1;
    }
}

extern "C" void kernel_launch(void* const* d_in, const int* in_sizes, int n_in,
                              void* d_out, int out_size, void* d_ws, size_t ws_size,
                              hipStream_t stream) {
    const float* Q = (const float*)d_in[0];
    const float* K = (const float*)d_in[1];
    const float* V = (const float*)d_in[2];
    // d_in[3] = mask: exact causal tril -> applied analytically.
    float* O = (float*)d_out;

    unsigned short* Kf = (unsigned short*)d_ws;                 // 8 MB
    unsigned short* Vf = Kf + (size_t)4194304;                  // 8 MB

    hipLaunchKernelGGL(prep_frag, dim3(1024), dim3(256), 0, stream, K, V, Kf, Vf);
    hipLaunchKernelGGL(attn_frag, dim3(512),  dim3(256), 0, stream, Q, Kf, Vf, O);
}